// Round 7
// baseline (751.457 us; speedup 1.0000x reference)
//
#include <hip/hip_runtime.h>

#define IN_DIM 256
#define HID 64
#define LAT 32
#define EPS 1e-5f
#define THREADS 256

static inline int cdiv(int a, int b){ return (a + b - 1) / b; }

// ---------- init: deg=1 (self loop), cnt=0, stats=0 ----------
__global__ void k_init(float* __restrict__ deg, int* __restrict__ cnt,
                       float* __restrict__ stats, int n){
  int i = blockIdx.x * blockDim.x + threadIdx.x;
  if (i < n){ deg[i] = 1.0f; cnt[i] = 0; }
  if (i < 192) stats[i] = 0.0f;
}

// ---------- degree + in-edge count ----------
__global__ void k_count(const int* __restrict__ ei, const float* __restrict__ ew,
                        float* __restrict__ deg, int* __restrict__ cnt, int E){
  int e = blockIdx.x * blockDim.x + threadIdx.x;
  if (e >= E) return;
  int c = ei[E + e];
  atomicAdd(&deg[c], ew[e]);
  atomicAdd(&cnt[c], 1);
}

// ---------- exclusive scan of cnt -> offs ----------
__global__ void k_scan1(const int* __restrict__ cnt, int* __restrict__ offs,
                        int* __restrict__ bsum, int n){
  __shared__ int lds[256];
  int t = threadIdx.x, b = blockIdx.x;
  int base = b * 2048 + t * 8;
  int v[8]; int s = 0;
  #pragma unroll
  for (int k = 0; k < 8; k++){ int idx = base + k; v[k] = (idx < n) ? cnt[idx] : 0; s += v[k]; }
  lds[t] = s; __syncthreads();
  for (int d = 1; d < 256; d <<= 1){
    int xv = (t >= d) ? lds[t - d] : 0;
    __syncthreads();
    lds[t] += xv;
    __syncthreads();
  }
  int excl = lds[t] - s;
  #pragma unroll
  for (int k = 0; k < 8; k++){ int idx = base + k; if (idx < n) offs[idx] = excl; excl += v[k]; }
  if (t == 0) bsum[b] = lds[255];
}

__global__ void k_scan2(int* __restrict__ bsum, int nb){
  __shared__ int lds[64];
  int t = threadIdx.x;
  int s = (t < nb) ? bsum[t] : 0;
  lds[t] = s; __syncthreads();
  for (int d = 1; d < 64; d <<= 1){
    int xv = (t >= d) ? lds[t - d] : 0;
    __syncthreads();
    lds[t] += xv;
    __syncthreads();
  }
  if (t < nb) bsum[t] = lds[t] - s;
}

// ---------- scan3 + dinv fused ----------
__global__ void k_scan3(int* __restrict__ offs, int* __restrict__ cur,
                        const int* __restrict__ bsum, float* __restrict__ deg, int n){
  int i = blockIdx.x * blockDim.x + threadIdx.x;
  if (i >= n) return;
  int o = offs[i] + bsum[i >> 11];
  offs[i] = o; cur[i] = o;
  deg[i] = rsqrtf(deg[i]);
}

// ---------- fill CSR, packed 8B edge records ----------
__global__ void k_fill(const int* __restrict__ ei, const float* __restrict__ ew,
                       const float* __restrict__ dinv, int* __restrict__ cur,
                       int2* __restrict__ edges, int E){
  int e = blockIdx.x * blockDim.x + threadIdx.x;
  if (e >= E) return;
  int r = ei[e], c = ei[E + e];
  int pos = atomicAdd(&cur[c], 1);
  edges[pos] = make_int2(r, __float_as_int(dinv[r] * ew[e] * dinv[c]));
}

// ---------- fused GEMM1: h1 = x@W1 ; xin = x@Wr + br ----------
// Row-major X in LDS, stride 65 (dword pad). Strided row ownership:
// thread (cg,rg) owns rows {rg,rg+32,rg+64,rg+96} x cols [8cg,8cg+8).
// Staging: coalesced f4 global read + 4 scalar LDS writes, banks
// (r+4k4+j)%32 -> 2-way max (free). Compute reads: Xl[rg+32i][lk],
// bank = rg -> conflict-free broadcast. W reads: b128 wave-broadcast.
#define G1_THREADS 384
#define G1_BM 128
#define G1_KC 64
__global__ __launch_bounds__(G1_THREADS, 2) void k_gemm1(
    const float* __restrict__ x, const float* __restrict__ W1,
    const float* __restrict__ Wr, const float* __restrict__ br,
    float* __restrict__ h1, float* __restrict__ xin, int n){
  __shared__ float Xl[G1_BM][G1_KC + 1];   // 128*65*4 = 33280 B
  __shared__ float Wl[G1_KC][96];          // 24576 B
  int t = threadIdx.x;
  int cg = t >> 5;          // 0..11 -> col group (8 cols)
  int rg = t & 31;          // 0..31 -> base row
  int row0 = blockIdx.x * G1_BM;
  int c0 = cg * 8;
  float acc[4][8];
  #pragma unroll
  for (int i = 0; i < 4; i++)
    #pragma unroll
    for (int j = 0; j < 8; j++) acc[i][j] = 0.f;

  for (int kc = 0; kc < IN_DIM; kc += G1_KC){
    // stage W1 chunk: 64x64 = 1024 f4 (row-major, bandwidth-bound, no conflict)
    for (int i = t; i < 1024; i += G1_THREADS){
      int k = i >> 4, c = (i & 15) << 2;
      *(float4*)&Wl[k][c] = *(const float4*)&W1[(size_t)(kc + k) * HID + c];
    }
    // stage Wr chunk: 64x32 = 512 f4
    for (int i = t; i < 512; i += G1_THREADS){
      int k = i >> 3, c = (i & 7) << 2;
      *(float4*)&Wl[k][64 + c] = *(const float4*)&Wr[(size_t)(kc + k) * LAT + c];
    }
    // stage X row-major: 2048 f4 reads -> 4 scalar writes each
    for (int i = t; i < 2048; i += G1_THREADS){
      int r = i >> 4, k4 = (i & 15) << 2;
      int grow = row0 + r;
      float4 v = (grow < n) ? *(const float4*)&x[(size_t)grow * IN_DIM + kc + k4]
                            : make_float4(0.f, 0.f, 0.f, 0.f);
      Xl[r][k4 + 0] = v.x; Xl[r][k4 + 1] = v.y;
      Xl[r][k4 + 2] = v.z; Xl[r][k4 + 3] = v.w;
    }
    __syncthreads();

    #pragma unroll 8
    for (int lk = 0; lk < G1_KC; lk++){
      float xs0 = Xl[rg      ][lk];
      float xs1 = Xl[rg + 32 ][lk];
      float xs2 = Xl[rg + 64 ][lk];
      float xs3 = Xl[rg + 96 ][lk];
      float4 wa = *(const float4*)&Wl[lk][c0];
      float4 wb = *(const float4*)&Wl[lk][c0 + 4];
      float wsv[8] = {wa.x, wa.y, wa.z, wa.w, wb.x, wb.y, wb.z, wb.w};
      #pragma unroll
      for (int j = 0; j < 8; j++){
        acc[0][j] = fmaf(xs0, wsv[j], acc[0][j]);
        acc[1][j] = fmaf(xs1, wsv[j], acc[1][j]);
        acc[2][j] = fmaf(xs2, wsv[j], acc[2][j]);
        acc[3][j] = fmaf(xs3, wsv[j], acc[3][j]);
      }
    }
    __syncthreads();
  }

  // epilogue: rows rg+32i; cols 0..63 -> h1, 64..95 -> xin (+br)
  #pragma unroll
  for (int i = 0; i < 4; i++){
    int row = row0 + rg + (i << 5);
    if (row >= n) continue;
    if (cg < 8){
      float* p = h1 + (size_t)row * HID + c0;
      *(float4*)(p)     = make_float4(acc[i][0], acc[i][1], acc[i][2], acc[i][3]);
      *(float4*)(p + 4) = make_float4(acc[i][4], acc[i][5], acc[i][6], acc[i][7]);
    } else {
      int cb = c0 - 64;
      float* p = xin + (size_t)row * LAT + cb;
      *(float4*)(p)     = make_float4(acc[i][0] + br[cb+0], acc[i][1] + br[cb+1],
                                      acc[i][2] + br[cb+2], acc[i][3] + br[cb+3]);
      *(float4*)(p + 4) = make_float4(acc[i][4] + br[cb+4], acc[i][5] + br[cb+5],
                                      acc[i][6] + br[cb+6], acc[i][7] + br[cb+7]);
    }
  }
}

// ---------- aggregation with packed edges ----------
template<int F>
__global__ void k_agg(const float* __restrict__ h, const int* __restrict__ offs,
                      const int* __restrict__ cnt, const int2* __restrict__ edges,
                      const float* __restrict__ dinv, float* __restrict__ out, int n){
  int gt = blockIdx.x * blockDim.x + threadIdx.x;
  int node = gt / F;
  int lane = gt & (F - 1);
  if (node >= n) return;
  float di = dinv[node];
  float acc = h[(size_t)node * F + lane] * (di * di);
  int j = offs[node];
  int e = j + cnt[node];
  for (; j + 3 < e; j += 4){
    int2 e0 = edges[j], e1 = edges[j+1], e2 = edges[j+2], e3 = edges[j+3];
    acc = fmaf(h[(size_t)e0.x * F + lane], __int_as_float(e0.y), acc);
    acc = fmaf(h[(size_t)e1.x * F + lane], __int_as_float(e1.y), acc);
    acc = fmaf(h[(size_t)e2.x * F + lane], __int_as_float(e2.y), acc);
    acc = fmaf(h[(size_t)e3.x * F + lane], __int_as_float(e3.y), acc);
  }
  for (; j < e; j++){
    int2 ee = edges[j];
    acc = fmaf(h[(size_t)ee.x * F + lane], __int_as_float(ee.y), acc);
  }
  out[(size_t)node * F + lane] = acc;
}

// ---------- batchnorm stats ----------
template<int F>
__global__ void k_bnstats(const float* __restrict__ a, float* __restrict__ sums,
                          float* __restrict__ sqs, int n){
  __shared__ float ls[256], lq[256];
  int t = threadIdx.x;
  int f = t & (F - 1);
  const int rpb = 256 / F;
  int r = blockIdx.x * rpb + t / F;
  int stride = gridDim.x * rpb;
  float s = 0.f, q = 0.f;
  for (; r < n; r += stride){
    float v = a[(size_t)r * F + f];
    s += v; q += v * v;
  }
  ls[t] = s; lq[t] = q; __syncthreads();
  if (t < F){
    for (int j = t + F; j < 256; j += F){ s += ls[j]; q += lq[j]; }
    atomicAdd(&sums[f], s);
    atomicAdd(&sqs[f], q);
  }
}

// ---------- finalize BN affine (conv bias cancels in BN) ----------
__global__ void k_bnfin(const float* __restrict__ sums, const float* __restrict__ sqs,
                        const float* __restrict__ g, const float* __restrict__ be,
                        float* __restrict__ scale, float* __restrict__ shift,
                        int n, int F){
  int f = threadIdx.x;
  if (f >= F) return;
  float inv_n = 1.0f / (float)n;
  float mean = sums[f] * inv_n;
  float var = sqs[f] * inv_n - mean * mean;
  float sc = g[f] * rsqrtf(var + EPS);
  scale[f] = sc;
  shift[f] = be[f] - mean * sc;
}

// ---------- fused BN1+PReLU+GEMM2: h2 = prelu(bn(agg1)) @ W2 ----------
// Same structure as gemm1: Yl row-major [128][33], strided row ownership.
#define G2_THREADS 128
#define G2_BM 128
#define G2_KC 32
__global__ __launch_bounds__(G2_THREADS, 2) void k_gemm2(
    const float* __restrict__ agg1, const float* __restrict__ scale,
    const float* __restrict__ shift, const float* __restrict__ prelu_a,
    const float* __restrict__ W2, float* __restrict__ h2, int n){
  __shared__ float Yl[G2_BM][G2_KC + 1];  // 128*33*4 = 16896 B
  __shared__ float Wl[HID][LAT];          // 8192 B
  int t = threadIdx.x;
  int cg = t >> 5;          // 0..3
  int rg = t & 31;          // 0..31
  int row0 = blockIdx.x * G2_BM;
  int c0 = cg * 8;
  float al = prelu_a[0];
  // stage W2 fully: 512 f4
  for (int i = t; i < 512; i += G2_THREADS){
    int k = i >> 3, c = (i & 7) << 2;
    *(float4*)&Wl[k][c] = *(const float4*)&W2[(size_t)k * LAT + c];
  }
  float acc[4][8];
  #pragma unroll
  for (int i = 0; i < 4; i++)
    #pragma unroll
    for (int j = 0; j < 8; j++) acc[i][j] = 0.f;

  for (int kc = 0; kc < HID; kc += G2_KC){
    __syncthreads();  // Wl ready (1st iter) / prev compute done reading Yl
    // stage y row-major: 1024 f4 reads -> BN+PReLU -> 4 scalar writes
    for (int i = t; i < 1024; i += G2_THREADS){
      int r = i >> 3, k4 = (i & 7) << 2;
      int grow = row0 + r;
      int gk = kc + k4;
      float4 v = (grow < n) ? *(const float4*)&agg1[(size_t)grow * HID + gk]
                            : make_float4(0.f, 0.f, 0.f, 0.f);
      float4 sc = *(const float4*)&scale[gk];
      float4 sh = *(const float4*)&shift[gk];
      float y0 = v.x * sc.x + sh.x; y0 = (y0 >= 0.f) ? y0 : al * y0;
      float y1 = v.y * sc.y + sh.y; y1 = (y1 >= 0.f) ? y1 : al * y1;
      float y2 = v.z * sc.z + sh.z; y2 = (y2 >= 0.f) ? y2 : al * y2;
      float y3 = v.w * sc.w + sh.w; y3 = (y3 >= 0.f) ? y3 : al * y3;
      Yl[r][k4 + 0] = y0; Yl[r][k4 + 1] = y1;
      Yl[r][k4 + 2] = y2; Yl[r][k4 + 3] = y3;
    }
    __syncthreads();
    #pragma unroll 8
    for (int lk = 0; lk < G2_KC; lk++){
      float ys0 = Yl[rg      ][lk];
      float ys1 = Yl[rg + 32 ][lk];
      float ys2 = Yl[rg + 64 ][lk];
      float ys3 = Yl[rg + 96 ][lk];
      float4 wa = *(const float4*)&Wl[kc + lk][c0];
      float4 wb = *(const float4*)&Wl[kc + lk][c0 + 4];
      float wsv[8] = {wa.x, wa.y, wa.z, wa.w, wb.x, wb.y, wb.z, wb.w};
      #pragma unroll
      for (int j = 0; j < 8; j++){
        acc[0][j] = fmaf(ys0, wsv[j], acc[0][j]);
        acc[1][j] = fmaf(ys1, wsv[j], acc[1][j]);
        acc[2][j] = fmaf(ys2, wsv[j], acc[2][j]);
        acc[3][j] = fmaf(ys3, wsv[j], acc[3][j]);
      }
    }
  }

  #pragma unroll
  for (int i = 0; i < 4; i++){
    int row = row0 + rg + (i << 5);
    if (row >= n) continue;
    float* p = h2 + (size_t)row * LAT + c0;
    *(float4*)(p)     = make_float4(acc[i][0], acc[i][1], acc[i][2], acc[i][3]);
    *(float4*)(p + 4) = make_float4(acc[i][4], acc[i][5], acc[i][6], acc[i][7]);
  }
}

// ---------- final: out = bn2(agg2) + xin ----------
__global__ void k_final(const float* __restrict__ agg2, const float* __restrict__ scale,
                        const float* __restrict__ shift, const float* __restrict__ xin,
                        float* __restrict__ out, int n){
  int i = blockIdx.x * blockDim.x + threadIdx.x;
  int total = n * (LAT / 4);
  if (i >= total) return;
  float4 a = ((const float4*)agg2)[i];
  float4 xi = ((const float4*)xin)[i];
  int f = (i * 4) & (LAT - 1);
  float4 o;
  o.x = a.x * scale[f+0] + shift[f+0] + xi.x;
  o.y = a.y * scale[f+1] + shift[f+1] + xi.y;
  o.z = a.z * scale[f+2] + shift[f+2] + xi.z;
  o.w = a.w * scale[f+3] + shift[f+3] + xi.w;
  ((float4*)out)[i] = o;
}

extern "C" void kernel_launch(void* const* d_in, const int* in_sizes, int n_in,
                              void* d_out, int out_size, void* d_ws, size_t ws_size,
                              hipStream_t stream){
  const float* x   = (const float*)d_in[0];
  const int*   ei  = (const int*)d_in[1];
  const float* ew  = (const float*)d_in[2];
  const float* W1  = (const float*)d_in[3];
  const float* g1  = (const float*)d_in[5];
  const float* be1 = (const float*)d_in[6];
  const float* W2  = (const float*)d_in[7];
  const float* g2  = (const float*)d_in[9];
  const float* be2 = (const float*)d_in[10];
  const float* pa  = (const float*)d_in[11];
  const float* Wr  = (const float*)d_in[12];
  const float* br  = (const float*)d_in[13];
  float* out = (float*)d_out;

  const int N = in_sizes[0] / IN_DIM;
  const int E = in_sizes[2];

  char* ws = (char*)d_ws;
  size_t o = 0;
  auto alloc = [&](size_t bytes)->char*{
    char* p = ws + o;
    o = (o + bytes + 255) & ~(size_t)255;
    return p;
  };
  float* deg   = (float*)alloc((size_t)N * 4);      // becomes dinv
  int*   cnt   = (int*)  alloc((size_t)N * 4);
  int*   offs  = (int*)  alloc((size_t)N * 4);
  int*   cur   = (int*)  alloc((size_t)N * 4);
  int*   bsum  = (int*)  alloc(64 * 4);
  float* stats = (float*)alloc(192 * 4);
  float* coef  = (float*)alloc(192 * 4);
  int2*  edges = (int2*) alloc((size_t)E * 8);
  float* bufA  = (float*)alloc((size_t)N * HID * 4); // h1, then h2
  float* bufB  = (float*)alloc((size_t)N * HID * 4); // agg1, then agg2
  float* xin   = (float*)alloc((size_t)N * LAT * 4);

  float* sums1 = stats, *sqs1 = stats + 64, *sums2 = stats + 128, *sqs2 = stats + 160;
  float* sc1 = coef, *sh1 = coef + 64, *sc2 = coef + 128, *sh2 = coef + 160;

  const int NB = cdiv(N, 2048);

  k_init<<<cdiv(N, THREADS), THREADS, 0, stream>>>(deg, cnt, stats, N);
  k_count<<<cdiv(E, THREADS), THREADS, 0, stream>>>(ei, ew, deg, cnt, E);
  k_scan1<<<NB, 256, 0, stream>>>(cnt, offs, bsum, N);
  k_scan2<<<1, 64, 0, stream>>>(bsum, NB);
  k_scan3<<<cdiv(N, THREADS), THREADS, 0, stream>>>(offs, cur, bsum, deg, N);
  k_fill<<<cdiv(E, THREADS), THREADS, 0, stream>>>(ei, ew, deg, cur, edges, E);

  k_gemm1<<<cdiv(N, G1_BM), G1_THREADS, 0, stream>>>(x, W1, Wr, br, bufA, xin, N);
  k_agg<HID><<<cdiv(N * HID, THREADS), THREADS, 0, stream>>>(bufA, offs, cnt, edges, deg, bufB, N);
  k_bnstats<HID><<<256, 256, 0, stream>>>(bufB, sums1, sqs1, N);
  k_bnfin<<<1, 64, 0, stream>>>(sums1, sqs1, g1, be1, sc1, sh1, N, HID);
  k_gemm2<<<cdiv(N, G2_BM), G2_THREADS, 0, stream>>>(bufB, sc1, sh1, pa, W2, bufA, N);
  k_agg<LAT><<<cdiv(N * LAT, THREADS), THREADS, 0, stream>>>(bufA, offs, cnt, edges, deg, bufB, N);
  k_bnstats<LAT><<<256, 256, 0, stream>>>(bufB, sums2, sqs2, N);
  k_bnfin<<<1, 32, 0, stream>>>(sums2, sqs2, g2, be2, sc2, sh2, N, LAT);
  k_final<<<cdiv(N * LAT / 4, THREADS), THREADS, 0, stream>>>(bufB, sc2, sh2, xin, out, N);
}

// Round 11
// 617.562 us; speedup vs baseline: 1.2168x; 1.2168x over previous
//
#include <hip/hip_runtime.h>
#include <hip/hip_bf16.h>

#define IN_DIM 256
#define HID 64
#define LAT 32
#define EPS 1e-5f
#define THREADS 256

typedef __attribute__((ext_vector_type(8))) short bf16x8;
typedef __attribute__((ext_vector_type(4))) float f32x4;

static inline int cdiv(int a, int b){ return (a + b - 1) / b; }

static __device__ inline unsigned short f2bf(float f){
  __hip_bfloat16 h = __float2bfloat16(f);
  union { __hip_bfloat16 h; unsigned short u; } cv; cv.h = h; return cv.u;
}

// ---------- init: deg=1 (self loop), cnt=0, stats=0 ----------
__global__ void k_init(float* __restrict__ deg, int* __restrict__ cnt,
                       float* __restrict__ stats, int n){
  int i = blockIdx.x * blockDim.x + threadIdx.x;
  if (i < n){ deg[i] = 1.0f; cnt[i] = 0; }
  if (i < 192) stats[i] = 0.0f;
}

// ---------- pre-transpose weights to bf16, K-contiguous ----------
// Wtg[96][256]: cols 0..63 = W1, 64..95 = Wr.  W2tg[32][64].
__global__ void k_prep(const float* __restrict__ W1, const float* __restrict__ Wr,
                       const float* __restrict__ W2, unsigned short* __restrict__ Wtg,
                       unsigned short* __restrict__ W2tg){
  int i = blockIdx.x * blockDim.x + threadIdx.x;
  if (i < 24576){
    int c = i % 96, k = i / 96;
    float v = (c < 64) ? W1[k * 64 + c] : Wr[k * 32 + (c - 64)];
    Wtg[c * 256 + k] = f2bf(v);
  } else if (i < 24576 + 2048){
    int j = i - 24576; int c = j % 32, k = j / 32;
    W2tg[c * 64 + k] = f2bf(W2[k * 32 + c]);
  }
}

// ---------- degree + in-edge count ----------
__global__ void k_count(const int* __restrict__ ei, const float* __restrict__ ew,
                        float* __restrict__ deg, int* __restrict__ cnt, int E){
  int e = blockIdx.x * blockDim.x + threadIdx.x;
  if (e >= E) return;
  int c = ei[E + e];
  atomicAdd(&deg[c], ew[e]);
  atomicAdd(&cnt[c], 1);
}

// ---------- exclusive scan of cnt -> offs ----------
__global__ void k_scan1(const int* __restrict__ cnt, int* __restrict__ offs,
                        int* __restrict__ bsum, int n){
  __shared__ int lds[256];
  int t = threadIdx.x, b = blockIdx.x;
  int base = b * 2048 + t * 8;
  int v[8]; int s = 0;
  #pragma unroll
  for (int k = 0; k < 8; k++){ int idx = base + k; v[k] = (idx < n) ? cnt[idx] : 0; s += v[k]; }
  lds[t] = s; __syncthreads();
  for (int d = 1; d < 256; d <<= 1){
    int xv = (t >= d) ? lds[t - d] : 0;
    __syncthreads();
    lds[t] += xv;
    __syncthreads();
  }
  int excl = lds[t] - s;
  #pragma unroll
  for (int k = 0; k < 8; k++){ int idx = base + k; if (idx < n) offs[idx] = excl; excl += v[k]; }
  if (t == 0) bsum[b] = lds[255];
}

__global__ void k_scan2(int* __restrict__ bsum, int nb){
  __shared__ int lds[64];
  int t = threadIdx.x;
  int s = (t < nb) ? bsum[t] : 0;
  lds[t] = s; __syncthreads();
  for (int d = 1; d < 64; d <<= 1){
    int xv = (t >= d) ? lds[t - d] : 0;
    __syncthreads();
    lds[t] += xv;
    __syncthreads();
  }
  if (t < nb) bsum[t] = lds[t] - s;
}

// ---------- scan3 + dinv fused ----------
__global__ void k_scan3(int* __restrict__ offs, int* __restrict__ cur,
                        const int* __restrict__ bsum, float* __restrict__ deg, int n){
  int i = blockIdx.x * blockDim.x + threadIdx.x;
  if (i >= n) return;
  int o = offs[i] + bsum[i >> 11];
  offs[i] = o; cur[i] = o;
  deg[i] = rsqrtf(deg[i]);
}

// ---------- fill CSR, packed 8B edge records ----------
__global__ void k_fill(const int* __restrict__ ei, const float* __restrict__ ew,
                       const float* __restrict__ dinv, int* __restrict__ cur,
                       int2* __restrict__ edges, int E){
  int e = blockIdx.x * blockDim.x + threadIdx.x;
  if (e >= E) return;
  int r = ei[e], c = ei[E + e];
  int pos = atomicAdd(&cur[c], 1);
  edges[pos] = make_int2(r, __float_as_int(dinv[r] * ew[e] * dinv[c]));
}

// ---------- MFMA GEMM1: h1 = x@W1 ; xin = x@Wr + br (bf16 inputs, fp32 acc) ----------
// 8 waves x 16 rows = 128 rows/block. K=256 held in A-frags (from global).
// Wt in LDS: [96 cols][264 bf16] (528B stride, /16 -> aligned b128, 2-way free).
// Per wave: 6 n-tiles x 8 k-steps = 48 mfma_f32_16x16x32_bf16; ONE barrier.
// A layout: lane holds A[row=l&15][k=(l>>4)*8+j]; B: B[k=(l>>4)*8+j][col=l&15];
// D: col=l&15, row=(l>>4)*4+reg (verified m89/m91).
__global__ __launch_bounds__(512, 2) void k_gemm1(
    const float* __restrict__ x, const unsigned short* __restrict__ Wtg,
    const float* __restrict__ br, float* __restrict__ h1,
    float* __restrict__ xin, int n){
  __shared__ alignas(16) unsigned short Wt[96 * 264];  // 50688 B
  int t = threadIdx.x;
  {
    const unsigned int* src = (const unsigned int*)Wtg;
    unsigned int* dst = (unsigned int*)Wt;
    for (int d = t; d < 12288; d += 512){
      int c = d >> 7, kd = d & 127;
      dst[c * 132 + kd] = src[d];   // bank (4c+kd)%32 -> conflict-free
    }
  }
  __syncthreads();

  int l = t & 63, w = t >> 6;
  int lm = l & 15, lg = l >> 4;
  int row0 = blockIdx.x * 128;
  int m = row0 + w * 16 + lm;

  union U { bf16x8 v; __hip_bfloat162 h[4]; };
  bf16x8 af[8];
  {
    bool ok = m < n;
    const float4* xr = (const float4*)(x + (size_t)m * IN_DIM);
    #pragma unroll
    for (int s = 0; s < 8; s++){
      float4 a0, a1;
      if (ok){ a0 = xr[s * 8 + lg * 2]; a1 = xr[s * 8 + lg * 2 + 1]; }
      else { a0 = make_float4(0.f,0.f,0.f,0.f); a1 = a0; }
      U u;
      u.h[0] = __float22bfloat162_rn(make_float2(a0.x, a0.y));
      u.h[1] = __float22bfloat162_rn(make_float2(a0.z, a0.w));
      u.h[2] = __float22bfloat162_rn(make_float2(a1.x, a1.y));
      u.h[3] = __float22bfloat162_rn(make_float2(a1.z, a1.w));
      af[s] = u.v;
    }
  }

  f32x4 acc[6];
  #pragma unroll
  for (int i = 0; i < 6; i++) acc[i] = (f32x4){0.f, 0.f, 0.f, 0.f};

  const char* wb = (const char*)Wt + lm * 528 + lg * 16;
  #pragma unroll
  for (int s = 0; s < 8; s++){
    #pragma unroll
    for (int tt = 0; tt < 6; tt++){
      bf16x8 bf = *(const bf16x8*)(wb + tt * 8448 + s * 64);
      acc[tt] = __builtin_amdgcn_mfma_f32_16x16x32_bf16(af[s], bf, acc[tt], 0, 0, 0);
    }
  }

  float br0 = br[lm], br1 = br[16 + lm];
  #pragma unroll
  for (int tt = 0; tt < 6; tt++){
    #pragma unroll
    for (int r = 0; r < 4; r++){
      int row = row0 + w * 16 + lg * 4 + r;
      if (row >= n) continue;
      if (tt < 4) h1[(size_t)row * HID + tt * 16 + lm] = acc[tt][r];
      else xin[(size_t)row * LAT + (tt - 4) * 16 + lm] = acc[tt][r] + (tt == 4 ? br0 : br1);
    }
  }
}

// ---------- aggregation with packed edges ----------
template<int F>
__global__ void k_agg(const float* __restrict__ h, const int* __restrict__ offs,
                      const int* __restrict__ cnt, const int2* __restrict__ edges,
                      const float* __restrict__ dinv, float* __restrict__ out, int n){
  int gt = blockIdx.x * blockDim.x + threadIdx.x;
  int node = gt / F;
  int lane = gt & (F - 1);
  if (node >= n) return;
  float di = dinv[node];
  float acc = h[(size_t)node * F + lane] * (di * di);
  int j = offs[node];
  int e = j + cnt[node];
  for (; j + 3 < e; j += 4){
    int2 e0 = edges[j], e1 = edges[j+1], e2 = edges[j+2], e3 = edges[j+3];
    acc = fmaf(h[(size_t)e0.x * F + lane], __int_as_float(e0.y), acc);
    acc = fmaf(h[(size_t)e1.x * F + lane], __int_as_float(e1.y), acc);
    acc = fmaf(h[(size_t)e2.x * F + lane], __int_as_float(e2.y), acc);
    acc = fmaf(h[(size_t)e3.x * F + lane], __int_as_float(e3.y), acc);
  }
  for (; j < e; j++){
    int2 ee = edges[j];
    acc = fmaf(h[(size_t)ee.x * F + lane], __int_as_float(ee.y), acc);
  }
  out[(size_t)node * F + lane] = acc;
}

// ---------- batchnorm stats ----------
template<int F>
__global__ void k_bnstats(const float* __restrict__ a, float* __restrict__ sums,
                          float* __restrict__ sqs, int n){
  __shared__ float ls[256], lq[256];
  int t = threadIdx.x;
  int f = t & (F - 1);
  const int rpb = 256 / F;
  int r = blockIdx.x * rpb + t / F;
  int stride = gridDim.x * rpb;
  float s = 0.f, q = 0.f;
  for (; r < n; r += stride){
    float v = a[(size_t)r * F + f];
    s += v; q += v * v;
  }
  ls[t] = s; lq[t] = q; __syncthreads();
  if (t < F){
    for (int j = t + F; j < 256; j += F){ s += ls[j]; q += lq[j]; }
    atomicAdd(&sums[f], s);
    atomicAdd(&sqs[f], q);
  }
}

// ---------- finalize BN affine (conv bias cancels in BN) ----------
__global__ void k_bnfin(const float* __restrict__ sums, const float* __restrict__ sqs,
                        const float* __restrict__ g, const float* __restrict__ be,
                        float* __restrict__ scale, float* __restrict__ shift,
                        int n, int F){
  int f = threadIdx.x;
  if (f >= F) return;
  float inv_n = 1.0f / (float)n;
  float mean = sums[f] * inv_n;
  float var = sqs[f] * inv_n - mean * mean;
  float sc = g[f] * rsqrtf(var + EPS);
  scale[f] = sc;
  shift[f] = be[f] - mean * sc;
}

// ---------- MFMA GEMM2: h2 = prelu(bn(agg1)) @ W2 ----------
// Same structure: 8 waves x 16 rows; BN+PReLU fused into A-frag build.
// W2t LDS: [32][72 bf16] (144B stride, b128-aligned, 2-way free).
__global__ __launch_bounds__(512, 2) void k_gemm2(
    const float* __restrict__ agg1, const float* __restrict__ scale,
    const float* __restrict__ shift, const float* __restrict__ prelu_a,
    const unsigned short* __restrict__ W2tg, float* __restrict__ h2, int n){
  __shared__ alignas(16) unsigned short W2t[32 * 72];  // 4608 B
  __shared__ float Scl[64], Shl[64];
  int t = threadIdx.x;
  {
    const unsigned int* src = (const unsigned int*)W2tg;
    unsigned int* dst = (unsigned int*)W2t;
    for (int d = t; d < 1024; d += 512){
      int c = d >> 5, kd = d & 31;
      dst[c * 36 + kd] = src[d];
    }
    if (t < 64){ Scl[t] = scale[t]; Shl[t] = shift[t]; }
  }
  __syncthreads();

  int l = t & 63, w = t >> 6;
  int lm = l & 15, lg = l >> 4;
  int row0 = blockIdx.x * 128;
  int m = row0 + w * 16 + lm;
  float al = prelu_a[0];

  union U { bf16x8 v; __hip_bfloat162 h[4]; };
  bf16x8 af[2];
  {
    bool ok = m < n;
    const float4* ar = (const float4*)(agg1 + (size_t)m * HID);
    #pragma unroll
    for (int s = 0; s < 2; s++){
      int kb = s * 32 + lg * 8;
      float4 a0, a1;
      if (ok){ a0 = ar[kb >> 2]; a1 = ar[(kb >> 2) + 1]; }
      else { a0 = make_float4(0.f,0.f,0.f,0.f); a1 = a0; }
      float4 sc0 = *(const float4*)&Scl[kb];
      float4 sc1 = *(const float4*)&Scl[kb + 4];
      float4 sh0 = *(const float4*)&Shl[kb];
      float4 sh1 = *(const float4*)&Shl[kb + 4];
      float y0 = a0.x * sc0.x + sh0.x; y0 = (y0 >= 0.f) ? y0 : al * y0;
      float y1 = a0.y * sc0.y + sh0.y; y1 = (y1 >= 0.f) ? y1 : al * y1;
      float y2 = a0.z * sc0.z + sh0.z; y2 = (y2 >= 0.f) ? y2 : al * y2;
      float y3 = a0.w * sc0.w + sh0.w; y3 = (y3 >= 0.f) ? y3 : al * y3;
      float y4 = a1.x * sc1.x + sh1.x; y4 = (y4 >= 0.f) ? y4 : al * y4;
      float y5 = a1.y * sc1.y + sh1.y; y5 = (y5 >= 0.f) ? y5 : al * y5;
      float y6 = a1.z * sc1.z + sh1.z; y6 = (y6 >= 0.f) ? y6 : al * y6;
      float y7 = a1.w * sc1.w + sh1.w; y7 = (y7 >= 0.f) ? y7 : al * y7;
      U u;
      u.h[0] = __float22bfloat162_rn(make_float2(y0, y1));
      u.h[1] = __float22bfloat162_rn(make_float2(y2, y3));
      u.h[2] = __float22bfloat162_rn(make_float2(y4, y5));
      u.h[3] = __float22bfloat162_rn(make_float2(y6, y7));
      af[s] = u.v;
    }
  }

  f32x4 acc[2];
  #pragma unroll
  for (int i = 0; i < 2; i++) acc[i] = (f32x4){0.f, 0.f, 0.f, 0.f};

  const char* wb = (const char*)W2t + lm * 144 + lg * 16;
  #pragma unroll
  for (int s = 0; s < 2; s++){
    #pragma unroll
    for (int tt = 0; tt < 2; tt++){
      bf16x8 bf = *(const bf16x8*)(wb + tt * 2304 + s * 64);
      acc[tt] = __builtin_amdgcn_mfma_f32_16x16x32_bf16(af[s], bf, acc[tt], 0, 0, 0);
    }
  }

  #pragma unroll
  for (int tt = 0; tt < 2; tt++){
    #pragma unroll
    for (int r = 0; r < 4; r++){
      int row = row0 + w * 16 + lg * 4 + r;
      if (row >= n) continue;
      h2[(size_t)row * LAT + tt * 16 + lm] = acc[tt][r];
    }
  }
}

// ---------- final: out = bn2(agg2) + xin ----------
__global__ void k_final(const float* __restrict__ agg2, const float* __restrict__ scale,
                        const float* __restrict__ shift, const float* __restrict__ xin,
                        float* __restrict__ out, int n){
  int i = blockIdx.x * blockDim.x + threadIdx.x;
  int total = n * (LAT / 4);
  if (i >= total) return;
  float4 a = ((const float4*)agg2)[i];
  float4 xi = ((const float4*)xin)[i];
  int f = (i * 4) & (LAT - 1);
  float4 o;
  o.x = a.x * scale[f+0] + shift[f+0] + xi.x;
  o.y = a.y * scale[f+1] + shift[f+1] + xi.y;
  o.z = a.z * scale[f+2] + shift[f+2] + xi.z;
  o.w = a.w * scale[f+3] + shift[f+3] + xi.w;
  ((float4*)out)[i] = o;
}

extern "C" void kernel_launch(void* const* d_in, const int* in_sizes, int n_in,
                              void* d_out, int out_size, void* d_ws, size_t ws_size,
                              hipStream_t stream){
  const float* x   = (const float*)d_in[0];
  const int*   ei  = (const int*)d_in[1];
  const float* ew  = (const float*)d_in[2];
  const float* W1  = (const float*)d_in[3];
  const float* g1  = (const float*)d_in[5];
  const float* be1 = (const float*)d_in[6];
  const float* W2  = (const float*)d_in[7];
  const float* g2  = (const float*)d_in[9];
  const float* be2 = (const float*)d_in[10];
  const float* pa  = (const float*)d_in[11];
  const float* Wr  = (const float*)d_in[12];
  const float* br  = (const float*)d_in[13];
  float* out = (float*)d_out;

  const int N = in_sizes[0] / IN_DIM;
  const int E = in_sizes[2];

  char* ws = (char*)d_ws;
  size_t o = 0;
  auto alloc = [&](size_t bytes)->char*{
    char* p = ws + o;
    o = (o + bytes + 255) & ~(size_t)255;
    return p;
  };
  float* deg   = (float*)alloc((size_t)N * 4);      // becomes dinv
  int*   cnt   = (int*)  alloc((size_t)N * 4);
  int*   offs  = (int*)  alloc((size_t)N * 4);
  int*   cur   = (int*)  alloc((size_t)N * 4);
  int*   bsum  = (int*)  alloc(64 * 4);
  float* stats = (float*)alloc(192 * 4);
  float* coef  = (float*)alloc(192 * 4);
  unsigned short* Wtg  = (unsigned short*)alloc(96 * 256 * 2);
  unsigned short* W2tg = (unsigned short*)alloc(32 * 64 * 2);
  int2*  edges = (int2*) alloc((size_t)E * 8);
  float* bufA  = (float*)alloc((size_t)N * HID * 4); // h1, then h2
  float* bufB  = (float*)alloc((size_t)N * HID * 4); // agg1, then agg2
  float* xin   = (float*)alloc((size_t)N * LAT * 4);

  float* sums1 = stats, *sqs1 = stats + 64, *sums2 = stats + 128, *sqs2 = stats + 160;
  float* sc1 = coef, *sh1 = coef + 64, *sc2 = coef + 128, *sh2 = coef + 160;

  const int NB = cdiv(N, 2048);

  k_init<<<cdiv(N, THREADS), THREADS, 0, stream>>>(deg, cnt, stats, N);
  k_prep<<<cdiv(24576 + 2048, THREADS), THREADS, 0, stream>>>(W1, Wr, W2, Wtg, W2tg);
  k_count<<<cdiv(E, THREADS), THREADS, 0, stream>>>(ei, ew, deg, cnt, E);
  k_scan1<<<NB, 256, 0, stream>>>(cnt, offs, bsum, N);
  k_scan2<<<1, 64, 0, stream>>>(bsum, NB);
  k_scan3<<<cdiv(N, THREADS), THREADS, 0, stream>>>(offs, cur, bsum, deg, N);
  k_fill<<<cdiv(E, THREADS), THREADS, 0, stream>>>(ei, ew, deg, cur, edges, E);

  k_gemm1<<<cdiv(N, 128), 512, 0, stream>>>(x, Wtg, br, bufA, xin, N);
  k_agg<HID><<<cdiv(N * HID, THREADS), THREADS, 0, stream>>>(bufA, offs, cnt, edges, deg, bufB, N);
  k_bnstats<HID><<<256, 256, 0, stream>>>(bufB, sums1, sqs1, N);
  k_bnfin<<<1, 64, 0, stream>>>(sums1, sqs1, g1, be1, sc1, sh1, N, HID);
  k_gemm2<<<cdiv(N, 128), 512, 0, stream>>>(bufB, sc1, sh1, pa, W2tg, bufA, N);
  k_agg<LAT><<<cdiv(N * LAT, THREADS), THREADS, 0, stream>>>(bufA, offs, cnt, edges, deg, bufB, N);
  k_bnstats<LAT><<<256, 256, 0, stream>>>(bufB, sums2, sqs2, N);
  k_bnfin<<<1, 32, 0, stream>>>(sums2, sqs2, g2, be2, sc2, sh2, N, LAT);
  k_final<<<cdiv(N * LAT / 4, THREADS), THREADS, 0, stream>>>(bufB, sc2, sh2, xin, out, N);
}

// Round 12
// 536.242 us; speedup vs baseline: 1.4013x; 1.1516x over previous
//
#include <hip/hip_runtime.h>
#include <hip/hip_bf16.h>

#define IN_DIM 256
#define HID 64
#define LAT 32
#define EPS 1e-5f
#define THREADS 256

typedef __attribute__((ext_vector_type(8))) short bf16x8;
typedef __attribute__((ext_vector_type(4))) float f32x4;

static inline int cdiv(int a, int b){ return (a + b - 1) / b; }

static __device__ inline unsigned short f2bf(float f){
  __hip_bfloat16 h = __float2bfloat16(f);
  union { __hip_bfloat16 h; unsigned short u; } cv; cv.h = h; return cv.u;
}
static __device__ inline float bf2f(unsigned short u){
  return __uint_as_float((unsigned)u << 16);
}

// ---------- init: degcnt=0, stats=0 ----------
__global__ void k_init(unsigned long long* __restrict__ degcnt,
                       float* __restrict__ stats, int n){
  int i = blockIdx.x * blockDim.x + threadIdx.x;
  if (i < n) degcnt[i] = 0ULL;
  if (i < 192) stats[i] = 0.0f;
}

// ---------- pre-transpose weights to bf16, K-contiguous ----------
__global__ void k_prep(const float* __restrict__ W1, const float* __restrict__ Wr,
                       const float* __restrict__ W2, unsigned short* __restrict__ Wtg,
                       unsigned short* __restrict__ W2tg){
  int i = blockIdx.x * blockDim.x + threadIdx.x;
  if (i < 24576){
    int c = i % 96, k = i / 96;
    float v = (c < 64) ? W1[k * 64 + c] : Wr[k * 32 + (c - 64)];
    Wtg[c * 256 + k] = f2bf(v);
  } else if (i < 24576 + 2048){
    int j = i - 24576; int c = j % 32, k = j / 32;
    W2tg[c * 64 + k] = f2bf(W2[k * 32 + c]);
  }
}

// ---------- degree+count in ONE packed 64-bit atomic ----------
// hi32 = count, lo32 = sum(w * 2^20) fixed point. Max node weight-sum ~50
// -> lo32 max ~5e7 << 2^32: no carry into hi32. Quantization 2^-20/edge.
__global__ void k_count(const int* __restrict__ ei, const float* __restrict__ ew,
                        unsigned long long* __restrict__ degcnt, int E){
  int e = blockIdx.x * blockDim.x + threadIdx.x;
  if (e >= E) return;
  int c = ei[E + e];
  unsigned long long pack = (1ULL << 32) |
      (unsigned long long)__float2uint_rn(ew[e] * 1048576.0f);
  atomicAdd(&degcnt[c], pack);
}

// ---------- exclusive scan of cnt(=hi32 of degcnt) -> offs ----------
__global__ void k_scan1(const unsigned long long* __restrict__ degcnt,
                        int* __restrict__ offs, int* __restrict__ bsum, int n){
  __shared__ int lds[256];
  int t = threadIdx.x, b = blockIdx.x;
  int base = b * 2048 + t * 8;
  int v[8]; int s = 0;
  #pragma unroll
  for (int k = 0; k < 8; k++){
    int idx = base + k;
    v[k] = (idx < n) ? (int)(degcnt[idx] >> 32) : 0;
    s += v[k];
  }
  lds[t] = s; __syncthreads();
  for (int d = 1; d < 256; d <<= 1){
    int xv = (t >= d) ? lds[t - d] : 0;
    __syncthreads();
    lds[t] += xv;
    __syncthreads();
  }
  int excl = lds[t] - s;
  #pragma unroll
  for (int k = 0; k < 8; k++){ int idx = base + k; if (idx < n) offs[idx] = excl; excl += v[k]; }
  if (t == 0) bsum[b] = lds[255];
}

__global__ void k_scan2(int* __restrict__ bsum, int nb){
  __shared__ int lds[64];
  int t = threadIdx.x;
  int s = (t < nb) ? bsum[t] : 0;
  lds[t] = s; __syncthreads();
  for (int d = 1; d < 64; d <<= 1){
    int xv = (t >= d) ? lds[t - d] : 0;
    __syncthreads();
    lds[t] += xv;
    __syncthreads();
  }
  if (t < nb) bsum[t] = lds[t] - s;
}

// ---------- scan3 + dinv (self-loop w=1 folded in) ----------
__global__ void k_scan3(int* __restrict__ offs, int* __restrict__ cur,
                        const int* __restrict__ bsum,
                        const unsigned long long* __restrict__ degcnt,
                        float* __restrict__ dinv, int n){
  int i = blockIdx.x * blockDim.x + threadIdx.x;
  if (i >= n) return;
  int o = offs[i] + bsum[i >> 11];
  offs[i] = o; cur[i] = o;
  float wsum = (float)(unsigned)(degcnt[i] & 0xFFFFFFFFu) * (1.0f / 1048576.0f);
  dinv[i] = rsqrtf(1.0f + wsum);
}

// ---------- fill CSR, packed 8B edge records ----------
// After this kernel cur[i] == offs[i] + cnt[i] == bucket end (reused by k_agg).
__global__ void k_fill(const int* __restrict__ ei, const float* __restrict__ ew,
                       const float* __restrict__ dinv, int* __restrict__ cur,
                       int2* __restrict__ edges, int E){
  int e = blockIdx.x * blockDim.x + threadIdx.x;
  if (e >= E) return;
  int r = ei[e], c = ei[E + e];
  int pos = atomicAdd(&cur[c], 1);
  edges[pos] = make_int2(r, __float_as_int(dinv[r] * ew[e] * dinv[c]));
}

// ---------- MFMA GEMM1: h1(bf16) = x@W1 ; xin = x@Wr + br ----------
__global__ __launch_bounds__(512, 2) void k_gemm1(
    const float* __restrict__ x, const unsigned short* __restrict__ Wtg,
    const float* __restrict__ br, unsigned short* __restrict__ h1,
    float* __restrict__ xin, int n){
  __shared__ alignas(16) unsigned short Wt[96 * 264];  // 50688 B
  int t = threadIdx.x;
  {
    const unsigned int* src = (const unsigned int*)Wtg;
    unsigned int* dst = (unsigned int*)Wt;
    for (int d = t; d < 12288; d += 512){
      int c = d >> 7, kd = d & 127;
      dst[c * 132 + kd] = src[d];   // bank (4c+kd)%32 -> conflict-free
    }
  }
  __syncthreads();

  int l = t & 63, w = t >> 6;
  int lm = l & 15, lg = l >> 4;
  int row0 = blockIdx.x * 128;
  int m = row0 + w * 16 + lm;

  union U { bf16x8 v; __hip_bfloat162 h[4]; };
  bf16x8 af[8];
  {
    bool ok = m < n;
    const float4* xr = (const float4*)(x + (size_t)m * IN_DIM);
    #pragma unroll
    for (int s = 0; s < 8; s++){
      float4 a0, a1;
      if (ok){ a0 = xr[s * 8 + lg * 2]; a1 = xr[s * 8 + lg * 2 + 1]; }
      else { a0 = make_float4(0.f,0.f,0.f,0.f); a1 = a0; }
      U u;
      u.h[0] = __float22bfloat162_rn(make_float2(a0.x, a0.y));
      u.h[1] = __float22bfloat162_rn(make_float2(a0.z, a0.w));
      u.h[2] = __float22bfloat162_rn(make_float2(a1.x, a1.y));
      u.h[3] = __float22bfloat162_rn(make_float2(a1.z, a1.w));
      af[s] = u.v;
    }
  }

  f32x4 acc[6];
  #pragma unroll
  for (int i = 0; i < 6; i++) acc[i] = (f32x4){0.f, 0.f, 0.f, 0.f};

  const char* wb = (const char*)Wt + lm * 528 + lg * 16;
  #pragma unroll
  for (int s = 0; s < 8; s++){
    #pragma unroll
    for (int tt = 0; tt < 6; tt++){
      bf16x8 bf = *(const bf16x8*)(wb + tt * 8448 + s * 64);
      acc[tt] = __builtin_amdgcn_mfma_f32_16x16x32_bf16(af[s], bf, acc[tt], 0, 0, 0);
    }
  }

  float br0 = br[lm], br1 = br[16 + lm];
  #pragma unroll
  for (int tt = 0; tt < 6; tt++){
    #pragma unroll
    for (int r = 0; r < 4; r++){
      int row = row0 + w * 16 + lg * 4 + r;
      if (row >= n) continue;
      if (tt < 4) h1[(size_t)row * HID + tt * 16 + lm] = f2bf(acc[tt][r]);
      else xin[(size_t)row * LAT + (tt - 4) * 16 + lm] = acc[tt][r] + (tt == 4 ? br0 : br1);
    }
  }
}

// ---------- aggregation: bf16 gathers, fp32 accumulate ----------
template<int F>
__global__ void k_agg(const unsigned short* __restrict__ h, const int* __restrict__ offs,
                      const int* __restrict__ endo, const int2* __restrict__ edges,
                      const float* __restrict__ dinv, float* __restrict__ out, int n){
  int gt = blockIdx.x * blockDim.x + threadIdx.x;
  int node = gt / F;
  int lane = gt & (F - 1);
  if (node >= n) return;
  float di = dinv[node];
  float acc = bf2f(h[(size_t)node * F + lane]) * (di * di);
  int j = offs[node];
  int e = endo[node];
  for (; j + 3 < e; j += 4){
    int2 e0 = edges[j], e1 = edges[j+1], e2 = edges[j+2], e3 = edges[j+3];
    acc = fmaf(bf2f(h[(size_t)e0.x * F + lane]), __int_as_float(e0.y), acc);
    acc = fmaf(bf2f(h[(size_t)e1.x * F + lane]), __int_as_float(e1.y), acc);
    acc = fmaf(bf2f(h[(size_t)e2.x * F + lane]), __int_as_float(e2.y), acc);
    acc = fmaf(bf2f(h[(size_t)e3.x * F + lane]), __int_as_float(e3.y), acc);
  }
  for (; j < e; j++){
    int2 ee = edges[j];
    acc = fmaf(bf2f(h[(size_t)ee.x * F + lane]), __int_as_float(ee.y), acc);
  }
  out[(size_t)node * F + lane] = acc;
}

// ---------- batchnorm stats ----------
template<int F>
__global__ void k_bnstats(const float* __restrict__ a, float* __restrict__ sums,
                          float* __restrict__ sqs, int n){
  __shared__ float ls[256], lq[256];
  int t = threadIdx.x;
  int f = t & (F - 1);
  const int rpb = 256 / F;
  int r = blockIdx.x * rpb + t / F;
  int stride = gridDim.x * rpb;
  float s = 0.f, q = 0.f;
  for (; r < n; r += stride){
    float v = a[(size_t)r * F + f];
    s += v; q += v * v;
  }
  ls[t] = s; lq[t] = q; __syncthreads();
  if (t < F){
    for (int j = t + F; j < 256; j += F){ s += ls[j]; q += lq[j]; }
    atomicAdd(&sums[f], s);
    atomicAdd(&sqs[f], q);
  }
}

// ---------- finalize BN affine (conv bias cancels in BN) ----------
__global__ void k_bnfin(const float* __restrict__ sums, const float* __restrict__ sqs,
                        const float* __restrict__ g, const float* __restrict__ be,
                        float* __restrict__ scale, float* __restrict__ shift,
                        int n, int F){
  int f = threadIdx.x;
  if (f >= F) return;
  float inv_n = 1.0f / (float)n;
  float mean = sums[f] * inv_n;
  float var = sqs[f] * inv_n - mean * mean;
  float sc = g[f] * rsqrtf(var + EPS);
  scale[f] = sc;
  shift[f] = be[f] - mean * sc;
}

// ---------- MFMA GEMM2: h2(bf16) = prelu(bn(agg1)) @ W2 ----------
__global__ __launch_bounds__(512, 2) void k_gemm2(
    const float* __restrict__ agg1, const float* __restrict__ scale,
    const float* __restrict__ shift, const float* __restrict__ prelu_a,
    const unsigned short* __restrict__ W2tg, unsigned short* __restrict__ h2, int n){
  __shared__ alignas(16) unsigned short W2t[32 * 72];  // 4608 B
  __shared__ float Scl[64], Shl[64];
  int t = threadIdx.x;
  {
    const unsigned int* src = (const unsigned int*)W2tg;
    unsigned int* dst = (unsigned int*)W2t;
    for (int d = t; d < 1024; d += 512){
      int c = d >> 5, kd = d & 31;
      dst[c * 36 + kd] = src[d];
    }
    if (t < 64){ Scl[t] = scale[t]; Shl[t] = shift[t]; }
  }
  __syncthreads();

  int l = t & 63, w = t >> 6;
  int lm = l & 15, lg = l >> 4;
  int row0 = blockIdx.x * 128;
  int m = row0 + w * 16 + lm;
  float al = prelu_a[0];

  union U { bf16x8 v; __hip_bfloat162 h[4]; };
  bf16x8 af[2];
  {
    bool ok = m < n;
    const float4* ar = (const float4*)(agg1 + (size_t)m * HID);
    #pragma unroll
    for (int s = 0; s < 2; s++){
      int kb = s * 32 + lg * 8;
      float4 a0, a1;
      if (ok){ a0 = ar[kb >> 2]; a1 = ar[(kb >> 2) + 1]; }
      else { a0 = make_float4(0.f,0.f,0.f,0.f); a1 = a0; }
      float4 sc0 = *(const float4*)&Scl[kb];
      float4 sc1 = *(const float4*)&Scl[kb + 4];
      float4 sh0 = *(const float4*)&Shl[kb];
      float4 sh1 = *(const float4*)&Shl[kb + 4];
      float y0 = a0.x * sc0.x + sh0.x; y0 = (y0 >= 0.f) ? y0 : al * y0;
      float y1 = a0.y * sc0.y + sh0.y; y1 = (y1 >= 0.f) ? y1 : al * y1;
      float y2 = a0.z * sc0.z + sh0.z; y2 = (y2 >= 0.f) ? y2 : al * y2;
      float y3 = a0.w * sc0.w + sh0.w; y3 = (y3 >= 0.f) ? y3 : al * y3;
      float y4 = a1.x * sc1.x + sh1.x; y4 = (y4 >= 0.f) ? y4 : al * y4;
      float y5 = a1.y * sc1.y + sh1.y; y5 = (y5 >= 0.f) ? y5 : al * y5;
      float y6 = a1.z * sc1.z + sh1.z; y6 = (y6 >= 0.f) ? y6 : al * y6;
      float y7 = a1.w * sc1.w + sh1.w; y7 = (y7 >= 0.f) ? y7 : al * y7;
      U u;
      u.h[0] = __float22bfloat162_rn(make_float2(y0, y1));
      u.h[1] = __float22bfloat162_rn(make_float2(y2, y3));
      u.h[2] = __float22bfloat162_rn(make_float2(y4, y5));
      u.h[3] = __float22bfloat162_rn(make_float2(y6, y7));
      af[s] = u.v;
    }
  }

  f32x4 acc[2];
  #pragma unroll
  for (int i = 0; i < 2; i++) acc[i] = (f32x4){0.f, 0.f, 0.f, 0.f};

  const char* wb = (const char*)W2t + lm * 144 + lg * 16;
  #pragma unroll
  for (int s = 0; s < 2; s++){
    #pragma unroll
    for (int tt = 0; tt < 2; tt++){
      bf16x8 bf = *(const bf16x8*)(wb + tt * 2304 + s * 64);
      acc[tt] = __builtin_amdgcn_mfma_f32_16x16x32_bf16(af[s], bf, acc[tt], 0, 0, 0);
    }
  }

  #pragma unroll
  for (int tt = 0; tt < 2; tt++){
    #pragma unroll
    for (int r = 0; r < 4; r++){
      int row = row0 + w * 16 + lg * 4 + r;
      if (row >= n) continue;
      h2[(size_t)row * LAT + tt * 16 + lm] = f2bf(acc[tt][r]);
    }
  }
}

// ---------- final: out = bn2(agg2) + xin ----------
__global__ void k_final(const float* __restrict__ agg2, const float* __restrict__ scale,
                        const float* __restrict__ shift, const float* __restrict__ xin,
                        float* __restrict__ out, int n){
  int i = blockIdx.x * blockDim.x + threadIdx.x;
  int total = n * (LAT / 4);
  if (i >= total) return;
  float4 a = ((const float4*)agg2)[i];
  float4 xi = ((const float4*)xin)[i];
  int f = (i * 4) & (LAT - 1);
  float4 o;
  o.x = a.x * scale[f+0] + shift[f+0] + xi.x;
  o.y = a.y * scale[f+1] + shift[f+1] + xi.y;
  o.z = a.z * scale[f+2] + shift[f+2] + xi.z;
  o.w = a.w * scale[f+3] + shift[f+3] + xi.w;
  ((float4*)out)[i] = o;
}

extern "C" void kernel_launch(void* const* d_in, const int* in_sizes, int n_in,
                              void* d_out, int out_size, void* d_ws, size_t ws_size,
                              hipStream_t stream){
  const float* x   = (const float*)d_in[0];
  const int*   ei  = (const int*)d_in[1];
  const float* ew  = (const float*)d_in[2];
  const float* W1  = (const float*)d_in[3];
  const float* g1  = (const float*)d_in[5];
  const float* be1 = (const float*)d_in[6];
  const float* W2  = (const float*)d_in[7];
  const float* g2  = (const float*)d_in[9];
  const float* be2 = (const float*)d_in[10];
  const float* pa  = (const float*)d_in[11];
  const float* Wr  = (const float*)d_in[12];
  const float* br  = (const float*)d_in[13];
  float* out = (float*)d_out;

  const int N = in_sizes[0] / IN_DIM;
  const int E = in_sizes[2];

  char* ws = (char*)d_ws;
  size_t o = 0;
  auto alloc = [&](size_t bytes)->char*{
    char* p = ws + o;
    o = (o + bytes + 255) & ~(size_t)255;
    return p;
  };
  unsigned long long* degcnt = (unsigned long long*)alloc((size_t)N * 8);
  float* dinv  = (float*)alloc((size_t)N * 4);
  int*   offs  = (int*)  alloc((size_t)N * 4);
  int*   cur   = (int*)  alloc((size_t)N * 4);   // after fill: bucket END offsets
  int*   bsum  = (int*)  alloc(64 * 4);
  float* stats = (float*)alloc(192 * 4);
  float* coef  = (float*)alloc(192 * 4);
  unsigned short* Wtg  = (unsigned short*)alloc(96 * 256 * 2);
  unsigned short* W2tg = (unsigned short*)alloc(32 * 64 * 2);
  int2*  edges = (int2*) alloc((size_t)E * 8);
  unsigned short* bufA = (unsigned short*)alloc((size_t)N * HID * 2); // h1(bf16), then h2
  float* bufB  = (float*)alloc((size_t)N * HID * 4); // agg1, then agg2 (fp32)
  float* xin   = (float*)alloc((size_t)N * LAT * 4);

  float* sums1 = stats, *sqs1 = stats + 64, *sums2 = stats + 128, *sqs2 = stats + 160;
  float* sc1 = coef, *sh1 = coef + 64, *sc2 = coef + 128, *sh2 = coef + 160;

  const int NB = cdiv(N, 2048);

  k_init<<<cdiv(N, THREADS), THREADS, 0, stream>>>(degcnt, stats, N);
  k_prep<<<cdiv(24576 + 2048, THREADS), THREADS, 0, stream>>>(W1, Wr, W2, Wtg, W2tg);
  k_count<<<cdiv(E, THREADS), THREADS, 0, stream>>>(ei, ew, degcnt, E);
  k_scan1<<<NB, 256, 0, stream>>>(degcnt, offs, bsum, N);
  k_scan2<<<1, 64, 0, stream>>>(bsum, NB);
  k_scan3<<<cdiv(N, THREADS), THREADS, 0, stream>>>(offs, cur, bsum, degcnt, dinv, N);
  k_fill<<<cdiv(E, THREADS), THREADS, 0, stream>>>(ei, ew, dinv, cur, edges, E);

  k_gemm1<<<cdiv(N, 128), 512, 0, stream>>>(x, Wtg, br, bufA, xin, N);
  k_agg<HID><<<cdiv(N * HID, THREADS), THREADS, 0, stream>>>(bufA, offs, cur, edges, dinv, bufB, N);
  k_bnstats<HID><<<256, 256, 0, stream>>>(bufB, sums1, sqs1, N);
  k_bnfin<<<1, 64, 0, stream>>>(sums1, sqs1, g1, be1, sc1, sh1, N, HID);
  k_gemm2<<<cdiv(N, 128), 512, 0, stream>>>(bufB, sc1, sh1, pa, W2tg, bufA, N);
  k_agg<LAT><<<cdiv(N * LAT, THREADS), THREADS, 0, stream>>>(bufA, offs, cur, edges, dinv, bufB, N);
  k_bnstats<LAT><<<256, 256, 0, stream>>>(bufB, sums2, sqs2, N);
  k_bnfin<<<1, 32, 0, stream>>>(sums2, sqs2, g2, be2, sc2, sh2, N, LAT);
  k_final<<<cdiv(N * LAT / 4, THREADS), THREADS, 0, stream>>>(bufB, sc2, sh2, xin, out, N);
}